// Round 3
// baseline (729.242 us; speedup 1.0000x reference)
//
#include <hip/hip_runtime.h>
#include <hip/hip_cooperative_groups.h>
#include <math.h>

namespace cg = cooperative_groups;

#define NB 8
#define NP 2048
#define TOLF 1e-4f
#define EPSF 1e-12f

// ---------------- 3x3 Kabsch (double, one-sided Jacobi SVD), per-lane ----------------
__device__ void kabsch3x3(const double Spq[9], const double Sp[3], const double Sq[3],
                          double R[9], double t[3]) {
    const double invN = 1.0 / (double)NP;
    double cs[3], ct[3];
#pragma unroll
    for (int i = 0; i < 3; ++i) { cs[i] = Sp[i] * invN; ct[i] = Sq[i] * invN; }
    double H[9];
#pragma unroll
    for (int i = 0; i < 3; ++i)
#pragma unroll
        for (int j = 0; j < 3; ++j)
            H[i * 3 + j] = Spq[i * 3 + j] - (double)NP * cs[i] * ct[j];

    double Bc[3][3], V[3][3];
#pragma unroll
    for (int j = 0; j < 3; ++j)
#pragma unroll
        for (int i = 0; i < 3; ++i) {
            Bc[j][i] = H[i * 3 + j];
            V[j][i]  = (i == j) ? 1.0 : 0.0;
        }
    for (int sweep = 0; sweep < 30; ++sweep) {
        bool rotated = false;
        for (int p = 0; p < 2; ++p)
            for (int q = p + 1; q < 3; ++q) {
                double app = 0, aqq = 0, apq = 0;
#pragma unroll
                for (int i = 0; i < 3; ++i) {
                    app += Bc[p][i] * Bc[p][i];
                    aqq += Bc[q][i] * Bc[q][i];
                    apq += Bc[p][i] * Bc[q][i];
                }
                if (apq * apq > 1e-60 + 1e-28 * app * aqq) {
                    rotated = true;
                    double tau = (aqq - app) / (2.0 * apq);
                    double tt  = (tau >= 0 ? 1.0 : -1.0) / (fabs(tau) + sqrt(1.0 + tau * tau));
                    double c   = 1.0 / sqrt(1.0 + tt * tt);
                    double sn  = c * tt;
#pragma unroll
                    for (int i = 0; i < 3; ++i) {
                        double bp = Bc[p][i], bq = Bc[q][i];
                        Bc[p][i] = c * bp - sn * bq;
                        Bc[q][i] = sn * bp + c * bq;
                        double vp = V[p][i], vq = V[q][i];
                        V[p][i] = c * vp - sn * vq;
                        V[q][i] = sn * vp + c * vq;
                    }
                }
            }
        if (!rotated) break;
    }
    double sv[3], U[3][3];
#pragma unroll
    for (int j = 0; j < 3; ++j) {
        sv[j] = sqrt(Bc[j][0] * Bc[j][0] + Bc[j][1] * Bc[j][1] + Bc[j][2] * Bc[j][2]);
        double inv = sv[j] > 0.0 ? 1.0 / sv[j] : 0.0;
#pragma unroll
        for (int i = 0; i < 3; ++i) U[j][i] = Bc[j][i] * inv;
    }
    double detH = H[0] * (H[4] * H[8] - H[5] * H[7])
                - H[1] * (H[3] * H[8] - H[5] * H[6])
                + H[2] * (H[3] * H[7] - H[4] * H[6]);
    double d = (detH >= 0.0) ? 1.0 : -1.0;
    int o[3] = {0, 1, 2};
    if (sv[o[0]] < sv[o[1]]) { int tmp = o[0]; o[0] = o[1]; o[1] = tmp; }
    if (sv[o[0]] < sv[o[2]]) { int tmp = o[0]; o[0] = o[2]; o[2] = tmp; }
    if (sv[o[1]] < sv[o[2]]) { int tmp = o[1]; o[1] = o[2]; o[2] = tmp; }
    double sg[3] = {1.0, 1.0, d};
#pragma unroll
    for (int i = 0; i < 3; ++i)
#pragma unroll
        for (int j = 0; j < 3; ++j) {
            double acc = 0.0;
#pragma unroll
            for (int k = 0; k < 3; ++k) acc += sg[k] * V[o[k]][i] * U[o[k]][j];
            R[i * 3 + j] = acc;
        }
#pragma unroll
    for (int i = 0; i < 3; ++i)
        t[i] = ct[i] - (R[i * 3 + 0] * cs[0] + R[i * 3 + 1] * cs[1] + R[i * 3 + 2] * cs[2]);
}

// ---------------- the whole ICP in one cooperative kernel ----------------
// grid: 256 blocks (8 batches x 32 src-chunks of 64 pts) x 256 threads.
// pc is implicit: pc = Tcum(psrc), Tcum maintained in fp64 by block 0.
__global__ __launch_bounds__(256, 1) void icp_kernel(
        const float* __restrict__ psrc, const float* __restrict__ ptgt,
        float* __restrict__ out,
        double* __restrict__ part,     // [256][16]
        double* __restrict__ Tc,       // [8][12] fp64 cumulative transform
        float* __restrict__ TcF,       // [8][12] fp32 copy for NN phase
        float* __restrict__ err,       // [8]
        int* __restrict__ done) {
    cg::grid_group grid = cg::this_grid();

    __shared__ float4 tg[2080];        // targets, padded: idx = j + (j>>6)
    __shared__ float4 ps[64];          // this block's 64 transformed src pts
    __shared__ float2 comb[32][66];    // per-tgtgroup winners, padded rows

    const int tid = threadIdx.x;
    const int bi  = blockIdx.x;
    const int b   = bi >> 5;           // batch
    const int sc  = bi & 31;           // src chunk

    // ---- init persistent state ----
    if (bi == 0 && tid < NB) {
        double* T = Tc + tid * 12;
        float*  F = TcF + tid * 12;
#pragma unroll
        for (int k = 0; k < 12; ++k) { T[k] = 0.0; F[k] = 0.0f; }
        T[0] = T[4] = T[8] = 1.0;
        F[0] = F[4] = F[8] = 1.0f;
        err[tid] = 0.0f;
        if (tid == 0) *done = 0;
    }
    grid.sync();

    for (int it = 0; it < 10; ++it) {
        // ================= phase A: NN + per-chunk fp64 reduction =================
        if (!*done) {
            const float* tb = ptgt + b * NP * 3;
            for (int j = tid; j < NP; j += 256) {
                float tx = tb[3 * j + 0], ty = tb[3 * j + 1], tz = tb[3 * j + 2];
                tg[j + (j >> 6)] = make_float4(tx, ty, tz,
                                               0.5f * (tx * tx + ty * ty + tz * tz));
            }
            if (tid < 64) {
                int s = sc * 64 + tid;
                const float* pp = psrc + (b * NP + s) * 3;
                float x = pp[0], y = pp[1], z = pp[2];
                const float* T = TcF + b * 12;
                ps[tid] = make_float4(T[0] * x + T[1] * y + T[2] * z + T[9],
                                      T[3] * x + T[4] * y + T[5] * z + T[10],
                                      T[6] * x + T[7] * y + T[8] * z + T[11], 0.0f);
            }
            __syncthreads();

            const int g   = tid & 7;    // src group (8 pts)
            const int tgp = tid >> 3;   // target group (64 targets)
            float sx[8], sy[8], sz[8], sm[8];
            int jm[8];
#pragma unroll
            for (int k = 0; k < 8; ++k) {
                float4 P = ps[g * 8 + k];
                sx[k] = P.x; sy[k] = P.y; sz[k] = P.z;
                sm[k] = INFINITY; jm[k] = 0;
            }
            const int base = tgp * 65, jbase = tgp * 64;
#pragma unroll 4
            for (int i = 0; i < 64; ++i) {
                float4 t = tg[base + i];
                int j = jbase + i;
#pragma unroll
                for (int k = 0; k < 8; ++k) {
                    float scv = t.w;
                    scv = fmaf(-sx[k], t.x, scv);
                    scv = fmaf(-sy[k], t.y, scv);
                    scv = fmaf(-sz[k], t.z, scv);
                    if (scv < sm[k]) { sm[k] = scv; jm[k] = j; }
                }
            }
#pragma unroll
            for (int k = 0; k < 8; ++k)
                comb[tgp][g * 8 + k] = make_float2(sm[k], __int_as_float(jm[k]));
            __syncthreads();

            if (tid < 64) {                       // wave 0: cross-group argmin + fp64
                float best = INFINITY; int bj = 0;
#pragma unroll 8
                for (int g2 = 0; g2 < 32; ++g2) { // ascending => first-min tie-break
                    float2 e = comb[g2][tid];
                    if (e.x < best) { best = e.x; bj = __float_as_int(e.y); }
                }
                float4 P = ps[tid];
                float a2 = P.x * P.x + P.y * P.y + P.z * P.z;
                float d2 = fmaf(2.0f, best, a2);
                float dist = sqrtf(fmaxf(d2, EPSF));
                float4 Q = tg[bj + (bj >> 6)];

                double v[16];
                v[0] = dist;
                v[1] = P.x; v[2] = P.y; v[3] = P.z;
                v[4] = Q.x; v[5] = Q.y; v[6] = Q.z;
                v[7]  = (double)P.x * Q.x; v[8]  = (double)P.x * Q.y; v[9]  = (double)P.x * Q.z;
                v[10] = (double)P.y * Q.x; v[11] = (double)P.y * Q.y; v[12] = (double)P.y * Q.z;
                v[13] = (double)P.z * Q.x; v[14] = (double)P.z * Q.y; v[15] = (double)P.z * Q.z;
#pragma unroll
                for (int k = 0; k < 16; ++k) {
                    double x = v[k];
#pragma unroll
                    for (int off = 32; off > 0; off >>= 1) x += __shfl_down(x, off);
                    v[k] = x;
                }
                if (tid == 0) {
                    double* dst = part + bi * 16;
#pragma unroll
                    for (int k = 0; k < 16; ++k) dst[k] = v[k];
                }
            }
        }
        grid.sync();

        // ================= phase B: global sums + Kabsch + compose (block 0) ========
        if (bi == 0 && tid < 64) {
            int done_old = *done;
            if (!done_old) {
                const int lb = tid >> 3, c8 = tid & 7;
                double acc[16];
#pragma unroll
                for (int k = 0; k < 16; ++k) acc[k] = 0.0;
                for (int cc = 0; cc < 4; ++cc) {
                    const double* pp = part + (lb * 32 + c8 * 4 + cc) * 16;
#pragma unroll
                    for (int k = 0; k < 16; ++k) acc[k] += pp[k];
                }
#pragma unroll
                for (int k = 0; k < 16; ++k) {
                    double x = acc[k];
                    x += __shfl_down(x, 4);
                    x += __shfl_down(x, 2);
                    x += __shfl_down(x, 1);
                    acc[k] = x;
                }
                int srcl = (tid < NB) ? tid * 8 : 0;
                double s[16];
#pragma unroll
                for (int k = 0; k < 16; ++k) s[k] = __shfl(acc[k], srcl);

                float errnew = 0.0f; bool conv = true;
                if (tid < NB) {
                    errnew = (float)(s[0] * (1.0 / (double)NP));
                    conv = fabsf(errnew - err[tid]) < TOLF;
                }
                unsigned long long m = __ballot(conv);
                int done_new = ((m & 0xFFull) == 0xFFull) ? 1 : 0;
                if (tid == 0) *done = done_new;
                if (!done_new && tid < NB) {
                    err[tid] = errnew;
                    double R[9], t[3];
                    kabsch3x3(&s[7], &s[1], &s[4], R, t);
                    double* T = Tc + tid * 12;
                    double Rn[9], tn[3];
#pragma unroll
                    for (int i = 0; i < 3; ++i) {
#pragma unroll
                        for (int j = 0; j < 3; ++j)
                            Rn[i * 3 + j] = R[i * 3 + 0] * T[0 + j]
                                          + R[i * 3 + 1] * T[3 + j]
                                          + R[i * 3 + 2] * T[6 + j];
                        tn[i] = R[i * 3 + 0] * T[9] + R[i * 3 + 1] * T[10]
                              + R[i * 3 + 2] * T[11] + t[i];
                    }
                    float* F = TcF + tid * 12;
#pragma unroll
                    for (int k = 0; k < 9; ++k) { T[k] = Rn[k]; F[k] = (float)Rn[k]; }
#pragma unroll
                    for (int k = 0; k < 3; ++k) { T[9 + k] = tn[k]; F[9 + k] = (float)tn[k]; }
                }
            }
        }
        grid.sync();
    }

    // ---- output: final Kabsch(psrc, Tcum(psrc)) == Tcum exactly ----
    if (bi == 0 && tid < NB) {
        const double* T = Tc + tid * 12;
        float* o = out + tid * 12;
#pragma unroll
        for (int i = 0; i < 3; ++i) {
#pragma unroll
            for (int j = 0; j < 3; ++j) o[i * 4 + j] = (float)T[i * 3 + j];
            o[i * 4 + 3] = (float)T[9 + i];
        }
    }
}

extern "C" void kernel_launch(void* const* d_in, const int* in_sizes, int n_in,
                              void* d_out, int out_size, void* d_ws, size_t ws_size,
                              hipStream_t stream) {
    const float* psrc = (const float*)d_in[0];
    const float* ptgt = (const float*)d_in[1];
    float* out = (float*)d_out;

    char* ws = (char*)d_ws;
    double* part = (double*)ws;                   // 256*16*8 = 32768 B
    double* Tc   = (double*)(ws + 32768);         // 768 B
    float*  TcF  = (float*)(ws + 32768 + 768);    // 384 B
    float*  err  = (float*)(ws + 32768 + 768 + 384);      // 32 B
    int*    done = (int*)(ws + 32768 + 768 + 384 + 32);   // 4 B

    void* args[] = {(void*)&psrc, (void*)&ptgt, (void*)&out, (void*)&part,
                    (void*)&Tc, (void*)&TcF, (void*)&err, (void*)&done};
    hipLaunchCooperativeKernel((const void*)icp_kernel, dim3(256), dim3(256),
                               args, 0, stream);
}